// Round 4
// baseline (38.698 us; speedup 1.0000x reference)
//
#include <hip/hip_runtime.h>
#include <math.h>

#define EPSV   1e-4f
#define DSCALE 1.25f   // 1/(1-0.2)

#define XSTR 29        // padded row stride (breaks stride-28 bank conflicts)
#define XIMG 812       // 28*29 floats per image
#define FLAG_MAGIC 0x1F2E3D4C

// ws layout (floats):
//   moP  [256][10]   @ 0       per-(c,b) mu_out partials      (bc = c*16+b)
//   s1P  [256][100]  @ 2560    per-(c,b) sc*T^T T partials
//   tmP  [256][2]    @ 28160   per-(c,b) [tr_c, mm_c]
//   flags[256] (int) @ 28672   handshake; producer sets MAGIC, reducer CAS->0

// One block per (b,c), b = bc&15 (reducers bc=0..15 spread across XCDs).
// Every block: conv of channel c over ALL batches (BN stats are batch-global),
// pool/BN/ELU/dropout for own batch, T = (f.W1)^T Xg, partials.
// c!=0: publish partials + release flag.  c==0: consume 15 flags, reduce, write out.
__global__ __launch_bounds__(256) void kFused(
    const float* __restrict__ x,      // [16,28,28,1]
    const int*   __restrict__ dmask,  // [16,12,12,16]
    const float* __restrict__ wconv,  // [5,5,1,16]
    const float* __restrict__ wsconv, // [16]
    const float* __restrict__ wfc,    // [2304,10]
    const float* __restrict__ wsfc,   // [10]
    float* __restrict__ moP, float* __restrict__ s1P, float* __restrict__ tmP,
    int*   __restrict__ flags,
    float* __restrict__ out)          // [160 mu | 1600 Sigma]
{
    __shared__ float xa_s[16 * XIMG];   // all 16 images, padded rows
    __shared__ float w_s[25];
    __shared__ float mu_s[576];         // own-batch conv out
    __shared__ float ra_s[256], rb_s[256];
    __shared__ float f_s[144], mud_s[144];
    __shared__ int   I_s[144];
    __shared__ float W2_s[1440];        // spatial-major fc rows (mu_out path)
    __shared__ float fW_s[1440];        // channel-major fc rows, scaled by f
    __shared__ float Xg_s[3600];        // [q][p] gathered argmax patches
    __shared__ float T_s[250];          // [p][u]
    __shared__ float stat_s[8];
    __shared__ float spfc_s[10];
    __shared__ float ownS_s[100], ownM_s[10];
    __shared__ float tmg_s[32];

    const int bc = blockIdx.x, b = bc & 15, c = bc >> 4, t = threadIdx.x;
    const bool is_red = (c == 0);

    // ---- stage all global inputs into LDS ----
    for (int j = t; j < 12544; j += 256) {
        const int bb = j / 784, rem = j - bb * 784;
        const int r = rem / 28, col = rem - r * 28;
        xa_s[bb * XIMG + r * XSTR + col] = x[j];
    }
    if (t < 25) w_s[t] = wconv[t * 16 + c];
    for (int j = t; j < 1440; j += 256) {
        const int q = j / 10, u = j - q * 10;
        W2_s[j] = wfc[(q * 16 + c) * 10 + u];   // row q*16+c (NHWC flatten)
        fW_s[j] = wfc[c * 1440 + j];            // row c*144+q (W1 view)
    }
    if (t < 10) spfc_s[t] = log1pf(expf(wsfc[t]));
    __syncthreads();

    // ---- conv (channel c) over all batches: 768 half-row tasks, 3/thread ----
    float s_acc = 0.f, q_acc = 0.f;
    for (int task = t; task < 768; task += 256) {
        const int bb = task / 48;
        const int hr = task - bb * 48;
        const int row = hr >> 1;
        const int x0 = (hr & 1) * 12;
        const float* xb = &xa_s[bb * XIMG + row * XSTR + x0];
        float acc[12];
#pragma unroll
        for (int j = 0; j < 12; j++) acc[j] = 0.f;
#pragma unroll
        for (int dy = 0; dy < 5; dy++) {
            const float* xr = xb + dy * XSTR;
            float rr[16];
#pragma unroll
            for (int j = 0; j < 16; j++) rr[j] = xr[j];
#pragma unroll
            for (int dx = 0; dx < 5; dx++) {
                const float wv = w_s[dy * 5 + dx];
#pragma unroll
                for (int j = 0; j < 12; j++)
                    acc[j] = fmaf(rr[j + dx], wv, acc[j]);
            }
        }
        const int obase = row * 24 + x0;
        if (bb == b) {
#pragma unroll
            for (int j = 0; j < 12; j++) mu_s[obase + j] = acc[j];
        }
#pragma unroll
        for (int j = 0; j < 12; j++) {
            s_acc += acc[j];
            q_acc = fmaf(acc[j], acc[j], q_acc);
        }
    }
    ra_s[t] = s_acc; rb_s[t] = q_acc;
    __syncthreads();
    for (int s = 128; s > 0; s >>= 1) {
        if (t < s) { ra_s[t] += ra_s[t + s]; rb_s[t] += rb_s[t + s]; }
        __syncthreads();
    }
    if (t == 0) {
        const float mean = ra_s[0] * (1.f / 9216.f);
        const float var  = rb_s[0] * (1.f / 9216.f) - mean * mean;
        stat_s[0] = mean;
        stat_s[1] = 1.f / sqrtf(var + EPSV);
        stat_s[2] = log1pf(expf(wsconv[c])) / (var + EPSV);  // sc
    }
    __syncthreads();

    // ---- pool (raw values: BN monotone, first-max ties) + BN + ELU + drop ----
    float trv = 0.f, mmv = 0.f;
    if (t < 144) {
        const int h = t / 12, w2 = t - h * 12;
        const int y0 = 2 * h, x0 = 2 * w2;
        const int i0 = y0 * 24 + x0;
        const float v00 = mu_s[i0], v01 = mu_s[i0 + 1];
        const float v10 = mu_s[i0 + 24], v11 = mu_s[i0 + 25];
        float best = v00; int arg = 0;
        if (v01 > best) { best = v01; arg = 1; }
        if (v10 > best) { best = v10; arg = 2; }
        if (v11 > best) { best = v11; arg = 3; }
        const int yy = y0 + (arg >> 1), xx = x0 + (arg & 1);
        const int i29 = yy * XSTR + xx;
        const float vn = (best - stat_s[0]) * stat_s[1];
        const float m = (dmask[((b * 12 + h) * 12 + w2) * 16 + c] != 0) ? 1.f : 0.f;
        const float g  = vn > 0.f ? 1.f : expf(vn);
        const float el = vn > 0.f ? vn  : expm1f(vn);
        const float fq = DSCALE * m * g;
        const float md = DSCALE * m * el;
        f_s[t] = fq; mud_s[t] = md; I_s[t] = i29;
        const float* xo = &xa_s[b * XIMG + i29];
        float pn = 0.f;
#pragma unroll
        for (int dy = 0; dy < 5; dy++)
#pragma unroll
            for (int dx = 0; dx < 5; dx++) {
                const float v = xo[dy * XSTR + dx];
                pn = fmaf(v, v, pn);
            }
        trv = stat_s[2] * fq * fq * pn;   // sc * f^2 * ||patch||^2
        mmv = md * md;
    }
    ra_s[t] = trv; rb_s[t] = mmv;
    __syncthreads();

    // ---- scale W1 rows by f; gather argmax patches ----
    for (int j = t; j < 1440; j += 256) fW_s[j] *= f_s[j / 10];
    {
        const int bo = b * XIMG;
        for (int e = t; e < 3600; e += 256) {
            const int q = e / 25, p = e - q * 25;
            Xg_s[e] = xa_s[bo + I_s[q] + (p / 5) * XSTR + (p % 5)];
        }
    }
    __syncthreads();
    for (int s = 128; s > 0; s >>= 1) {
        if (t < s) { ra_s[t] += ra_s[t + s]; rb_s[t] += rb_s[t + s]; }
        __syncthreads();
    }
    // ra_s[0] = tr_c, rb_s[0] = mm_c

    // ---- T[p,u] = sum_q fW[q,u] * Xg[q,p] ----
    if (t < 250) {
        const int p = t / 10, u = t - p * 10;
        float acc = 0.f;
#pragma unroll 8
        for (int q = 0; q < 144; q++)
            acc = fmaf(fW_s[q * 10 + u], Xg_s[q * 25 + p], acc);
        T_s[t] = acc;
    }
    __syncthreads();

    // ---- per-(b,c) partials ----
    float sig_val = 0.f, mu_val = 0.f;
    if (t < 100) {
        const int u = t / 10, v = t - (t / 10) * 10;
        float acc = 0.f;
#pragma unroll
        for (int p = 0; p < 25; p++)
            acc = fmaf(T_s[p * 10 + u], T_s[p * 10 + v], acc);
        sig_val = stat_s[2] * acc;                 // sc * (T^T T)
    } else if (t < 110) {
        const int u = t - 100;
        float acc = 0.f;
#pragma unroll 8
        for (int q = 0; q < 144; q++)
            acc = fmaf(mud_s[q], W2_s[q * 10 + u], acc);
        mu_val = acc;
    }

    if (!is_red) {
        // -------- producer: publish partials, release flag --------
        if (t < 100)      s1P[bc * 100 + t] = sig_val;
        else if (t < 110) moP[bc * 10 + (t - 100)] = mu_val;
        if (t == 0) { tmP[bc * 2 + 0] = ra_s[0]; tmP[bc * 2 + 1] = rb_s[0]; }
        __threadfence();          // agent-scope visibility of the stores above
        __syncthreads();
        if (t == 0)
            __hip_atomic_store(&flags[bc], FLAG_MAGIC, __ATOMIC_RELEASE,
                               __HIP_MEMORY_SCOPE_AGENT);
    } else {
        // -------- reducer: own partials to LDS, consume 15 flags, reduce --------
        if (t < 100)      ownS_s[t] = sig_val;
        else if (t < 110) ownM_s[t - 100] = mu_val;
        __syncthreads();
        if (t < 15) {
            const int idx = (t + 1) * 16 + b;       // peer block bc = cc*16+b
            while (true) {
                int expected = FLAG_MAGIC;
                if (__hip_atomic_compare_exchange_strong(&flags[idx], &expected, 0,
                        __ATOMIC_ACQUIRE, __ATOMIC_RELAXED, __HIP_MEMORY_SCOPE_AGENT))
                    break;
                __builtin_amdgcn_s_sleep(1);
            }
        }
        __syncthreads();
        if (t < 30) {
            const int cc = 1 + (t >> 1);
            tmg_s[t] = __hip_atomic_load(&tmP[(cc * 16 + b) * 2 + (t & 1)],
                                         __ATOMIC_RELAXED, __HIP_MEMORY_SCOPE_AGENT);
        }
        __syncthreads();
        if (t == 0) {
            float a = ra_s[0] + rb_s[0];            // own tr + mm
            for (int i = 0; i < 30; i++) a += tmg_s[i];
            stat_s[5] = a;                          // total trace + mu.mu
        }
        __syncthreads();
        if (t < 100) {
            const int u = t / 10, v = t - (t / 10) * 10;
            float acc = ownS_s[t];
#pragma unroll
            for (int cc = 1; cc < 16; cc++)
                acc += __hip_atomic_load(&s1P[(cc * 16 + b) * 100 + t],
                                         __ATOMIC_RELAXED, __HIP_MEMORY_SCOPE_AGENT);
            if (u == v) acc += spfc_s[u] * stat_s[5];
            out[160 + b * 100 + t] = acc;
        } else if (t < 110) {
            const int u = t - 100;
            float acc = ownM_s[u];
#pragma unroll
            for (int cc = 1; cc < 16; cc++)
                acc += __hip_atomic_load(&moP[(cc * 16 + b) * 10 + u],
                                         __ATOMIC_RELAXED, __HIP_MEMORY_SCOPE_AGENT);
            out[b * 10 + u] = acc;
        }
    }
}

extern "C" void kernel_launch(void* const* d_in, const int* in_sizes, int n_in,
                              void* d_out, int out_size, void* d_ws, size_t ws_size,
                              hipStream_t stream) {
    const float* x      = (const float*)d_in[0];
    const int*   dmask  = (const int*)d_in[1];
    const float* wconv  = (const float*)d_in[2];
    const float* wsconv = (const float*)d_in[3];
    const float* wfc    = (const float*)d_in[4];
    const float* wsfc   = (const float*)d_in[5];
    float* out = (float*)d_out;

    float* ws   = (float*)d_ws;
    float* moP  = ws;            // 2560
    float* s1P  = ws + 2560;     // 25600
    float* tmP  = ws + 28160;    // 512
    int*   flags = (int*)(ws + 28672); // 256 ints

    kFused<<<256, 256, 0, stream>>>(x, dmask, wconv, wsconv, wfc, wsfc,
                                    moP, s1P, tmP, flags, out);
}

// Round 5
// 22.291 us; speedup vs baseline: 1.7360x; 1.7360x over previous
//
#include <hip/hip_runtime.h>
#include <math.h>

#define EPSV   1e-4f
#define DSCALE 1.25f   // 1/(1-0.2)

#define XSTR 30        // padded row stride (even -> float2; odd/32 bank spread)
#define XIMG 840       // 28*30 floats per image
#define QPAD 148       // padded q-stride for fWT/XgT (mult of 4 -> b128 aligned)
#define FLAG_MAGIC 0x1F2E3D4C

// ws layout (floats):
//   moP  [256][10]   @ 0      per-(c,b) mu_out partials      (bc = c*16+b)
//   s1P  [256][100]  @ 2560   per-(c,b) sc*T^T T partials
//   tmP  [256]       @ 28160  per-(c,b) tr_c + mm_c
//   flags[256*32]    @ 28416  (int) one flag per 128B line
//
// All cross-block traffic uses relaxed AGENT-scope atomics (sc1: write-through
// to the memory-side coherent point) -> no threadfence / no cache-wide ops.

__device__ __forceinline__ float wave_sum(float v) {
#pragma unroll
    for (int off = 32; off > 0; off >>= 1) v += __shfl_down(v, off, 64);
    return v;
}

__global__ __launch_bounds__(256) void kFused(
    const float* __restrict__ x,      // [16,28,28,1]
    const int*   __restrict__ dmask,  // [16,12,12,16]
    const float* __restrict__ wconv,  // [5,5,1,16]
    const float* __restrict__ wsconv, // [16]
    const float* __restrict__ wfc,    // [2304,10]
    const float* __restrict__ wsfc,   // [10]
    float* __restrict__ moP, float* __restrict__ s1P, float* __restrict__ tmP,
    int*   __restrict__ flags,
    float* __restrict__ out)          // [160 mu | 1600 Sigma]
{
    __shared__ float xa_s[16 * XIMG];   // 53.8 KB: all 16 images, padded rows
    __shared__ float w_s[25];
    __shared__ float mu_s[576];         // own-batch conv out
    __shared__ float red_s[8];          // wave partial sums
    __shared__ float f_s[144], mud_s[144];
    __shared__ int   I_s[144];          // argmax pos as yy*XSTR+xx
    __shared__ float W2_s[1440];        // spatial-major fc rows (mu_out path)
    __shared__ float fWT_s[10 * QPAD];  // f[q]*W1[c,q,u], u-major padded
    __shared__ float XgT_s[25 * QPAD];  // gathered patches, p-major padded
    __shared__ float T_s[250];          // [p][u]
    __shared__ float stat_s[8];         // mean,istd,sc,tm_c,total_tm
    __shared__ float spfc_s[10];
    __shared__ float tmg_s[16];

    const int bc = blockIdx.x, b = bc & 15, c = bc >> 4, t = threadIdx.x;
    const bool is_red = (c == 0);

    // ---- stage inputs into LDS ----
    for (int j = t; j < 12544; j += 256) {
        const int bb = j / 784, rem = j - bb * 784;
        const int r = rem / 28, col = rem - r * 28;
        xa_s[bb * XIMG + r * XSTR + col] = x[j];
    }
    if (t < 25) w_s[t] = wconv[t * 16 + c];
    for (int j = t; j < 1440; j += 256) {
        const int q = j / 10, u = j - q * 10;
        W2_s[j] = wfc[(q * 16 + c) * 10 + u];   // NHWC-flatten row q*16+c
    }
    if (t < 10) spfc_s[t] = log1pf(expf(wsfc[t]));
    __syncthreads();

    // ---- conv (channel c) over all batches: 768 half-row tasks, 3/thread ----
    float s_acc = 0.f, q_acc = 0.f;
    for (int task = t; task < 768; task += 256) {
        const int bb = task / 48;
        const int hr = task - bb * 48;
        const int row = hr >> 1;
        const int x0 = (hr & 1) * 12;
        const float* xb = &xa_s[bb * XIMG + row * XSTR + x0];
        float acc[12];
#pragma unroll
        for (int j = 0; j < 12; j++) acc[j] = 0.f;
#pragma unroll
        for (int dy = 0; dy < 5; dy++) {
            const float2* xr2 = (const float2*)(xb + dy * XSTR);
            float rr[16];
#pragma unroll
            for (int k = 0; k < 8; k++) {
                const float2 v = xr2[k];
                rr[2 * k] = v.x; rr[2 * k + 1] = v.y;
            }
#pragma unroll
            for (int dx = 0; dx < 5; dx++) {
                const float wv = w_s[dy * 5 + dx];
#pragma unroll
                for (int j = 0; j < 12; j++)
                    acc[j] = fmaf(rr[j + dx], wv, acc[j]);
            }
        }
        const int obase = row * 24 + x0;
        if (bb == b) {
#pragma unroll
            for (int j = 0; j < 12; j++) mu_s[obase + j] = acc[j];
        }
#pragma unroll
        for (int j = 0; j < 12; j++) {
            s_acc += acc[j];
            q_acc = fmaf(acc[j], acc[j], q_acc);
        }
    }
    {
        const float ws1 = wave_sum(s_acc), ws2 = wave_sum(q_acc);
        if ((t & 63) == 0) { red_s[t >> 6] = ws1; red_s[4 + (t >> 6)] = ws2; }
    }
    __syncthreads();
    if (t == 0) {
        const float ts = red_s[0] + red_s[1] + red_s[2] + red_s[3];
        const float tq = red_s[4] + red_s[5] + red_s[6] + red_s[7];
        const float mean = ts * (1.f / 9216.f);
        const float var  = tq * (1.f / 9216.f) - mean * mean;
        stat_s[0] = mean;
        stat_s[1] = 1.f / sqrtf(var + EPSV);
        stat_s[2] = log1pf(expf(wsconv[c])) / (var + EPSV);  // sc
    }
    __syncthreads();

    // ---- pool (raw: BN monotone, first-max ties) + BN + ELU + dropout ----
    float trv = 0.f, mmv = 0.f;
    if (t < 144) {
        const int h = t / 12, w2 = t - h * 12;
        const int y0 = 2 * h, x0 = 2 * w2;
        const int i0 = y0 * 24 + x0;
        const float v00 = mu_s[i0], v01 = mu_s[i0 + 1];
        const float v10 = mu_s[i0 + 24], v11 = mu_s[i0 + 25];
        float best = v00; int arg = 0;
        if (v01 > best) { best = v01; arg = 1; }
        if (v10 > best) { best = v10; arg = 2; }
        if (v11 > best) { best = v11; arg = 3; }
        const int yy = y0 + (arg >> 1), xx = x0 + (arg & 1);
        const int ipos = yy * XSTR + xx;
        const float vn = (best - stat_s[0]) * stat_s[1];
        const float m = (dmask[((b * 12 + h) * 12 + w2) * 16 + c] != 0) ? 1.f : 0.f;
        const float g  = vn > 0.f ? 1.f : expf(vn);
        const float el = vn > 0.f ? vn  : expm1f(vn);
        const float fq = DSCALE * m * g;
        const float md = DSCALE * m * el;
        f_s[t] = fq; mud_s[t] = md; I_s[t] = ipos;
        const float* xo = &xa_s[b * XIMG + ipos];
        float pn = 0.f;
#pragma unroll
        for (int dy = 0; dy < 5; dy++)
#pragma unroll
            for (int dx = 0; dx < 5; dx++) {
                const float v = xo[dy * XSTR + dx];
                pn = fmaf(v, v, pn);
            }
        trv = stat_s[2] * fq * fq * pn;   // sc * f^2 * ||patch||^2
        mmv = md * md;
    }
    {
        const float wt = wave_sum(trv), wm = wave_sum(mmv);
        if ((t & 63) == 0) { red_s[t >> 6] = wt; red_s[4 + (t >> 6)] = wm; }
    }
    __syncthreads();

    // ---- build fWT[u][q], gather XgT[p][q]; t0 folds tr_c+mm_c ----
    for (int j = t; j < 1440; j += 256) {
        const int q = j / 10, u = j - q * 10;
        fWT_s[u * QPAD + q] = f_s[q] * wfc[c * 1440 + j];
    }
    {
        const int bo = b * XIMG;
        for (int e = t; e < 3600; e += 256) {
            const int p = e / 144, q = e - p * 144;
            XgT_s[p * QPAD + q] = xa_s[bo + I_s[q] + (p / 5) * XSTR + (p % 5)];
        }
    }
    if (t == 0)
        stat_s[3] = red_s[0] + red_s[1] + red_s[2] + red_s[3]
                  + red_s[4] + red_s[5] + red_s[6] + red_s[7];   // tm_c
    __syncthreads();

    // ---- T[p,u] = sum_q fWT[u,q] * XgT[p,q]  (b128 LDS reads) ----
    if (t < 250) {
        const int p = t / 10, u = t - (t / 10) * 10;
        const float4* fa = (const float4*)&fWT_s[u * QPAD];
        const float4* xg = (const float4*)&XgT_s[p * QPAD];
        float acc = 0.f;
#pragma unroll 6
        for (int k = 0; k < 36; k++) {
            const float4 a = fa[k], g4 = xg[k];
            acc = fmaf(a.x, g4.x, acc);
            acc = fmaf(a.y, g4.y, acc);
            acc = fmaf(a.z, g4.z, acc);
            acc = fmaf(a.w, g4.w, acc);
        }
        T_s[t] = acc;
    }
    __syncthreads();

    // ---- per-(b,c) partials ----
    float sig_val = 0.f, mu_val = 0.f;
    if (t < 100) {
        const int u = t / 10, v = t - (t / 10) * 10;
        float acc = 0.f;
#pragma unroll
        for (int p = 0; p < 25; p++)
            acc = fmaf(T_s[p * 10 + u], T_s[p * 10 + v], acc);
        sig_val = stat_s[2] * acc;                 // sc * (T^T T)
    } else if (t < 110) {
        const int u = t - 100;
        float acc = 0.f;
#pragma unroll 8
        for (int q = 0; q < 144; q++)
            acc = fmaf(mud_s[q], W2_s[q * 10 + u], acc);
        mu_val = acc;
    }

    if (!is_red) {
        // ---- producer: sc1 publish, drain, flag ----
        if (t < 100)
            __hip_atomic_store(&s1P[bc * 100 + t], sig_val,
                               __ATOMIC_RELAXED, __HIP_MEMORY_SCOPE_AGENT);
        else if (t < 110)
            __hip_atomic_store(&moP[bc * 10 + (t - 100)], mu_val,
                               __ATOMIC_RELAXED, __HIP_MEMORY_SCOPE_AGENT);
        else if (t == 110)
            __hip_atomic_store(&tmP[bc], stat_s[3],
                               __ATOMIC_RELAXED, __HIP_MEMORY_SCOPE_AGENT);
        asm volatile("s_waitcnt vmcnt(0)" ::: "memory");
        __syncthreads();
        if (t == 0)
            __hip_atomic_store(&flags[bc * 32], FLAG_MAGIC,
                               __ATOMIC_RELAXED, __HIP_MEMORY_SCOPE_AGENT);
    } else {
        // ---- reducer: relaxed-load spin (no CAS, padded lines), reduce ----
        if (t < 15) {
            const int idx = ((t + 1) * 16 + b) * 32;
            while (__hip_atomic_load(&flags[idx], __ATOMIC_RELAXED,
                                     __HIP_MEMORY_SCOPE_AGENT) != FLAG_MAGIC)
                __builtin_amdgcn_s_sleep(2);
            __hip_atomic_store(&flags[idx], 0,
                               __ATOMIC_RELAXED, __HIP_MEMORY_SCOPE_AGENT);
        }
        __syncthreads();
        if (t < 15)
            tmg_s[t] = __hip_atomic_load(&tmP[(t + 1) * 16 + b],
                                         __ATOMIC_RELAXED, __HIP_MEMORY_SCOPE_AGENT);
        __syncthreads();
        if (t == 0) {
            float a = stat_s[3];
            for (int i = 0; i < 15; i++) a += tmg_s[i];
            stat_s[5] = a;                          // total trace + mu.mu
        }
        __syncthreads();
        if (t < 100) {
            const int u = t / 10, v = t - (t / 10) * 10;
            float acc = sig_val;
#pragma unroll
            for (int cc = 1; cc < 16; cc++)
                acc += __hip_atomic_load(&s1P[(cc * 16 + b) * 100 + t],
                                         __ATOMIC_RELAXED, __HIP_MEMORY_SCOPE_AGENT);
            if (u == v) acc += spfc_s[u] * stat_s[5];
            out[160 + b * 100 + t] = acc;
        } else if (t < 110) {
            const int u = t - 100;
            float acc = mu_val;
#pragma unroll
            for (int cc = 1; cc < 16; cc++)
                acc += __hip_atomic_load(&moP[(cc * 16 + b) * 10 + u],
                                         __ATOMIC_RELAXED, __HIP_MEMORY_SCOPE_AGENT);
            out[b * 10 + u] = acc;
        }
    }
}

extern "C" void kernel_launch(void* const* d_in, const int* in_sizes, int n_in,
                              void* d_out, int out_size, void* d_ws, size_t ws_size,
                              hipStream_t stream) {
    const float* x      = (const float*)d_in[0];
    const int*   dmask  = (const int*)d_in[1];
    const float* wconv  = (const float*)d_in[2];
    const float* wsconv = (const float*)d_in[3];
    const float* wfc    = (const float*)d_in[4];
    const float* wsfc   = (const float*)d_in[5];
    float* out = (float*)d_out;

    float* ws    = (float*)d_ws;
    float* moP   = ws;               // 2560
    float* s1P   = ws + 2560;        // 25600
    float* tmP   = ws + 28160;       // 256
    int*   flags = (int*)(ws + 28416); // 256*32 ints (128B-padded lines)

    kFused<<<256, 256, 0, stream>>>(x, dmask, wconv, wsconv, wfc, wsfc,
                                    moP, s1P, tmP, flags, out);
}

// Round 6
// 21.248 us; speedup vs baseline: 1.8212x; 1.0491x over previous
//
#include <hip/hip_runtime.h>
#include <math.h>

#define EPSV   1e-4f
#define DSCALE 1.25f   // 1/(1-0.2)

#define XSTR 30        // padded row stride (even -> float2; good bank spread)
#define XIMG 840       // 28*30 floats per image
#define QPAD 148       // padded q-stride for fWT/XgT (mult of 4 -> b128 aligned)
#define FLAG_MAGIC 0x1F2E3D4C

// ws layout (floats):
//   moP  [256][10]   @ 0      per-(c,b) mu_out partials      (bc = c*16+b)
//   s1P  [256][100]  @ 2560   per-(c,b) sc*T^T T partials
//   tmP  [256]       @ 28160  per-(c,b) tr_c + mm_c
//   flags[256*32]    @ 28416  (int) one flag per 128B line
//
// Cross-block traffic: relaxed AGENT-scope atomics (write-through, no cache
// maintenance ops). Producer drains vmcnt, barrier, then sets flag.

__device__ __forceinline__ float wave_sum(float v) {
#pragma unroll
    for (int off = 32; off > 0; off >>= 1) v += __shfl_down(v, off, 64);
    return v;
}

__global__ __launch_bounds__(256) void kFused(
    const float* __restrict__ x,      // [16,28,28,1]
    const int*   __restrict__ dmask,  // [16,12,12,16]
    const float* __restrict__ wconv,  // [5,5,1,16]
    const float* __restrict__ wsconv, // [16]
    const float* __restrict__ wfc,    // [2304,10]
    const float* __restrict__ wsfc,   // [10]
    float* __restrict__ moP, float* __restrict__ s1P, float* __restrict__ tmP,
    int*   __restrict__ flags,
    float* __restrict__ out)          // [160 mu | 1600 Sigma]
{
    __shared__ __align__(16) float xa_s[16 * XIMG];   // all 16 images, padded
    __shared__ __align__(16) float W1_s[1440];        // wfc rows c*144..+144 (W1 view)
    __shared__ __align__(8)  float W2_s[1440];        // spatial-major fc rows
    __shared__ __align__(16) float fWT_s[10 * QPAD];  // f[q]*W1[c,q,u], u-major
    __shared__ __align__(16) float XgT_s[25 * QPAD];  // gathered patches, p-major
    __shared__ float w_s[25];
    __shared__ float mu_s[576];
    __shared__ float red_s[8];
    __shared__ float f_s[144], mud_s[144];
    __shared__ int   I_s[144];
    __shared__ float T_s[250];
    __shared__ float stat_s[8];
    __shared__ float spfc_s[10];
    __shared__ float tmg_s[16];

    const int bc = blockIdx.x, b = bc & 15, c = bc >> 4, t = threadIdx.x;
    const bool is_red = (c == 0);

    // ================= prologue: ALL global loads issued here =================
    const int dm = (t < 144) ? dmask[b * 2304 + t * 16 + c] : 0;  // own mask bit
    const float wsc_v = wsconv[c];                                 // uniform s_load

    // x: 3136 float4 loads, 2x ds_write_b64 each (28%4==0 -> float4 in-row)
    {
        const float4* x4 = (const float4*)x;
        for (int j4 = t; j4 < 3136; j4 += 256) {
            const int bb  = j4 / 196;
            const int rem = j4 - bb * 196;
            const int r   = rem / 7;
            const int c4  = (rem - r * 7) * 4;
            const float4 v = x4[j4];
            float* dst = &xa_s[bb * XIMG + r * XSTR + c4];
            ((float2*)dst)[0] = make_float2(v.x, v.y);
            ((float2*)dst)[1] = make_float2(v.z, v.w);
        }
    }
    // W1 slice: contiguous 1440 floats -> 360 float4
    {
        const float4* wfc4 = (const float4*)wfc;
        for (int j4 = t; j4 < 360; j4 += 256)
            ((float4*)W1_s)[j4] = wfc4[c * 360 + j4];
    }
    // W2: rows q*16+c of wfc, float2 (global offset (q*16+c)*10 always even)
    {
        const float2* wfc2 = (const float2*)wfc;
        for (int j2 = t; j2 < 720; j2 += 256) {
            const int q = j2 / 5, uh = j2 - q * 5;
            ((float2*)W2_s)[j2] = wfc2[(q * 16 + c) * 5 + uh];
        }
    }
    if (t < 25) w_s[t] = wconv[t * 16 + c];
    if (t < 10) spfc_s[t] = log1pf(expf(wsfc[t]));
    __syncthreads();

    // ========== conv (channel c) over all batches: 768 half-row tasks ==========
    float s_acc = 0.f, q_acc = 0.f;
    for (int task = t; task < 768; task += 256) {
        const int bb = task / 48;
        const int hr = task - bb * 48;
        const int row = hr >> 1;
        const int x0 = (hr & 1) * 12;
        const float* xb = &xa_s[bb * XIMG + row * XSTR + x0];
        float acc[12];
#pragma unroll
        for (int j = 0; j < 12; j++) acc[j] = 0.f;
#pragma unroll
        for (int dy = 0; dy < 5; dy++) {
            const float2* xr2 = (const float2*)(xb + dy * XSTR);
            float rr[16];
#pragma unroll
            for (int k = 0; k < 8; k++) {
                const float2 v = xr2[k];
                rr[2 * k] = v.x; rr[2 * k + 1] = v.y;
            }
#pragma unroll
            for (int dx = 0; dx < 5; dx++) {
                const float wv = w_s[dy * 5 + dx];
#pragma unroll
                for (int j = 0; j < 12; j++)
                    acc[j] = fmaf(rr[j + dx], wv, acc[j]);
            }
        }
        const int obase = row * 24 + x0;
        if (bb == b) {
#pragma unroll
            for (int j = 0; j < 12; j++) mu_s[obase + j] = acc[j];
        }
#pragma unroll
        for (int j = 0; j < 12; j++) {
            s_acc += acc[j];
            q_acc = fmaf(acc[j], acc[j], q_acc);
        }
    }
    {
        const float ws1 = wave_sum(s_acc), ws2 = wave_sum(q_acc);
        if ((t & 63) == 0) { red_s[t >> 6] = ws1; red_s[4 + (t >> 6)] = ws2; }
    }
    __syncthreads();
    if (t == 0) {
        const float ts = red_s[0] + red_s[1] + red_s[2] + red_s[3];
        const float tq = red_s[4] + red_s[5] + red_s[6] + red_s[7];
        const float mean = ts * (1.f / 9216.f);
        const float var  = tq * (1.f / 9216.f) - mean * mean;
        stat_s[0] = mean;
        stat_s[1] = 1.f / sqrtf(var + EPSV);
        stat_s[2] = log1pf(expf(wsc_v)) / (var + EPSV);  // sc
    }
    __syncthreads();

    // ===== pool (raw: BN monotone, first-max ties) + BN + ELU + dropout =====
    float trv = 0.f, mmv = 0.f;
    if (t < 144) {
        const int h = t / 12, w2 = t - h * 12;
        const int y0 = 2 * h, x0 = 2 * w2;
        const int i0 = y0 * 24 + x0;
        const float v00 = mu_s[i0], v01 = mu_s[i0 + 1];
        const float v10 = mu_s[i0 + 24], v11 = mu_s[i0 + 25];
        float best = v00; int arg = 0;
        if (v01 > best) { best = v01; arg = 1; }
        if (v10 > best) { best = v10; arg = 2; }
        if (v11 > best) { best = v11; arg = 3; }
        const int yy = y0 + (arg >> 1), xx = x0 + (arg & 1);
        const int ipos = yy * XSTR + xx;
        const float vn = (best - stat_s[0]) * stat_s[1];
        const float m = (dm != 0) ? 1.f : 0.f;
        const float g  = vn > 0.f ? 1.f : expf(vn);
        const float el = vn > 0.f ? vn  : expm1f(vn);
        const float fq = DSCALE * m * g;
        const float md = DSCALE * m * el;
        f_s[t] = fq; mud_s[t] = md; I_s[t] = ipos;
        const float* xo = &xa_s[b * XIMG + ipos];
        float pn = 0.f;
#pragma unroll
        for (int dy = 0; dy < 5; dy++)
#pragma unroll
            for (int dx = 0; dx < 5; dx++) {
                const float v = xo[dy * XSTR + dx];
                pn = fmaf(v, v, pn);
            }
        trv = stat_s[2] * fq * fq * pn;   // sc * f^2 * ||patch||^2
        mmv = md * md;
    }
    {
        const float wt = wave_sum(trv), wm = wave_sum(mmv);
        if ((t & 63) == 0) { red_s[t >> 6] = wt; red_s[4 + (t >> 6)] = wm; }
    }
    __syncthreads();

    // ---- build fWT[u][q] (from LDS W1), gather XgT[p][q]; fold tr_c+mm_c ----
    for (int j = t; j < 1440; j += 256) {
        const int q = j / 10, u = j - q * 10;
        fWT_s[u * QPAD + q] = f_s[q] * W1_s[j];
    }
    {
        const int bo = b * XIMG;
        for (int e = t; e < 3600; e += 256) {
            const int p = e / 144, q = e - p * 144;
            XgT_s[p * QPAD + q] = xa_s[bo + I_s[q] + (p / 5) * XSTR + (p % 5)];
        }
    }
    if (t == 0)
        stat_s[3] = red_s[0] + red_s[1] + red_s[2] + red_s[3]
                  + red_s[4] + red_s[5] + red_s[6] + red_s[7];   // tm_c
    __syncthreads();

    // ---- T[p,u] = sum_q fWT[u,q] * XgT[p,q]  (b128 LDS reads) ----
    if (t < 250) {
        const int p = t / 10, u = t - (t / 10) * 10;
        const float4* fa = (const float4*)&fWT_s[u * QPAD];
        const float4* xg = (const float4*)&XgT_s[p * QPAD];
        float acc = 0.f;
#pragma unroll 6
        for (int k = 0; k < 36; k++) {
            const float4 a = fa[k], g4 = xg[k];
            acc = fmaf(a.x, g4.x, acc);
            acc = fmaf(a.y, g4.y, acc);
            acc = fmaf(a.z, g4.z, acc);
            acc = fmaf(a.w, g4.w, acc);
        }
        T_s[t] = acc;
    }
    __syncthreads();

    // ---- per-(b,c) partials ----
    float sig_val = 0.f, mu_val = 0.f;
    if (t < 100) {
        const int u = t / 10, v = t - (t / 10) * 10;
        float acc = 0.f;
#pragma unroll
        for (int p = 0; p < 25; p++)
            acc = fmaf(T_s[p * 10 + u], T_s[p * 10 + v], acc);
        sig_val = stat_s[2] * acc;                 // sc * (T^T T)
    } else if (t < 110) {
        const int u = t - 100;
        float acc = 0.f;
#pragma unroll 8
        for (int q = 0; q < 144; q++)
            acc = fmaf(mud_s[q], W2_s[q * 10 + u], acc);
        mu_val = acc;
    }

    if (!is_red) {
        // ---- producer: publish partials, drain, flag ----
        if (t < 100)
            __hip_atomic_store(&s1P[bc * 100 + t], sig_val,
                               __ATOMIC_RELAXED, __HIP_MEMORY_SCOPE_AGENT);
        else if (t < 110)
            __hip_atomic_store(&moP[bc * 10 + (t - 100)], mu_val,
                               __ATOMIC_RELAXED, __HIP_MEMORY_SCOPE_AGENT);
        else if (t == 110)
            __hip_atomic_store(&tmP[bc], stat_s[3],
                               __ATOMIC_RELAXED, __HIP_MEMORY_SCOPE_AGENT);
        asm volatile("s_waitcnt vmcnt(0)" ::: "memory");
        __syncthreads();
        if (t == 0)
            __hip_atomic_store(&flags[bc * 32], FLAG_MAGIC,
                               __ATOMIC_RELAXED, __HIP_MEMORY_SCOPE_AGENT);
    } else {
        // ---- reducer: relaxed-load spin (padded lines), reduce, write out ----
        if (t < 15) {
            const int idx = ((t + 1) * 16 + b) * 32;
            while (__hip_atomic_load(&flags[idx], __ATOMIC_RELAXED,
                                     __HIP_MEMORY_SCOPE_AGENT) != FLAG_MAGIC)
                __builtin_amdgcn_s_sleep(2);
            __hip_atomic_store(&flags[idx], 0,
                               __ATOMIC_RELAXED, __HIP_MEMORY_SCOPE_AGENT);
        }
        __syncthreads();
        if (t < 15)
            tmg_s[t] = __hip_atomic_load(&tmP[(t + 1) * 16 + b],
                                         __ATOMIC_RELAXED, __HIP_MEMORY_SCOPE_AGENT);
        __syncthreads();
        if (t == 0) {
            float a = stat_s[3];
            for (int i = 0; i < 15; i++) a += tmg_s[i];
            stat_s[5] = a;                          // total trace + mu.mu
        }
        __syncthreads();
        if (t < 100) {
            const int u = t / 10, v = t - (t / 10) * 10;
            float acc = sig_val;
#pragma unroll
            for (int cc = 1; cc < 16; cc++)
                acc += __hip_atomic_load(&s1P[(cc * 16 + b) * 100 + t],
                                         __ATOMIC_RELAXED, __HIP_MEMORY_SCOPE_AGENT);
            if (u == v) acc += spfc_s[u] * stat_s[5];
            out[160 + b * 100 + t] = acc;
        } else if (t < 110) {
            const int u = t - 100;
            float acc = mu_val;
#pragma unroll
            for (int cc = 1; cc < 16; cc++)
                acc += __hip_atomic_load(&moP[(cc * 16 + b) * 10 + u],
                                         __ATOMIC_RELAXED, __HIP_MEMORY_SCOPE_AGENT);
            out[b * 10 + u] = acc;
        }
    }
}

extern "C" void kernel_launch(void* const* d_in, const int* in_sizes, int n_in,
                              void* d_out, int out_size, void* d_ws, size_t ws_size,
                              hipStream_t stream) {
    const float* x      = (const float*)d_in[0];
    const int*   dmask  = (const int*)d_in[1];
    const float* wconv  = (const float*)d_in[2];
    const float* wsconv = (const float*)d_in[3];
    const float* wfc    = (const float*)d_in[4];
    const float* wsfc   = (const float*)d_in[5];
    float* out = (float*)d_out;

    float* ws    = (float*)d_ws;
    float* moP   = ws;               // 2560
    float* s1P   = ws + 2560;        // 25600
    float* tmP   = ws + 28160;       // 256
    int*   flags = (int*)(ws + 28416); // 256*32 ints (128B-padded lines)

    kFused<<<256, 256, 0, stream>>>(x, dmask, wconv, wsconv, wfc, wsfc,
                                    moP, s1P, tmP, flags, out);
}

// Round 7
// 18.336 us; speedup vs baseline: 2.1105x; 1.1588x over previous
//
#include <hip/hip_runtime.h>
#include <math.h>

#define EPSV   1e-4f
#define DSCALE 1.25f   // 1/(1-0.2)

#define XSTR 30        // padded row stride (even -> float2-aligned windows)
#define XIMG 840       // 28*30 floats per image
#define QPAD 148       // padded q-stride for fWT/XgT (mult of 4 -> b128 aligned)
#define FLAG_MAGIC 0x1F2E3D4C

// ws layout (floats):
//   moP   [256][10]     @ 0       per-(c,b) mu_out partials   (bc = c*16+b)
//   s1P   [256][100]    @ 2560    per-(c,b) sc*T^T T partials
//   tmP   [256]         @ 28160   per-(c,b) tr_c + mm_c
//   flagB [256*32] int  @ 28416   output handshake (c!=0 -> c==0 reducer)
//   flagA [256*32] int  @ 36608   BN-partials ready (per block)
//   dataA [256*32]      @ 44800   (psum, psq) per block
//   flagS [256*32] int  @ 52992   per-consumer stats ready
//   dataS [256*32]      @ 61184   (mean, istd, sc) per consumer line
//
// All cross-block traffic: relaxed AGENT-scope atomics (write-through; no
// cache-maintenance ops). Publisher: data stores -> s_waitcnt vmcnt(0) ->
// flag store (same thread or barrier-ordered). Consumer resets every flag it
// consumes -> state self-restores each graph replay. DAG: A -> S -> B -> out.

__device__ __forceinline__ float wave_sum(float v) {
#pragma unroll
    for (int off = 32; off > 0; off >>= 1) v += __shfl_down(v, off, 64);
    return v;
}

#define AG_LD(p)    __hip_atomic_load((p), __ATOMIC_RELAXED, __HIP_MEMORY_SCOPE_AGENT)
#define AG_ST(p, v) __hip_atomic_store((p), (v), __ATOMIC_RELAXED, __HIP_MEMORY_SCOPE_AGENT)

__global__ __launch_bounds__(256) void kFused(
    const float* __restrict__ x,      // [16,28,28,1]
    const int*   __restrict__ dmask,  // [16,12,12,16]
    const float* __restrict__ wconv,  // [5,5,1,16]
    const float* __restrict__ wsconv, // [16]
    const float* __restrict__ wfc,    // [2304,10]
    const float* __restrict__ wsfc,   // [10]
    float* __restrict__ moP, float* __restrict__ s1P, float* __restrict__ tmP,
    int* __restrict__ flagB, int* __restrict__ flagA, float* __restrict__ dataA,
    int* __restrict__ flagS, float* __restrict__ dataS,
    float* __restrict__ out)          // [160 mu | 1600 Sigma]
{
    __shared__ __align__(16) float xa_s[XIMG];        // own image only
    __shared__ __align__(16) float W1_s[1440];        // wfc rows c*144.. (W1 view)
    __shared__ __align__(8)  float W2_s[1440];        // spatial-major fc rows
    __shared__ __align__(16) float fWT_s[10 * QPAD];  // f[q]*W1[c,q,u], u-major
    __shared__ __align__(16) float XgT_s[25 * QPAD];  // gathered patches, p-major
    __shared__ float w_s[25];
    __shared__ float red_s[8];
    __shared__ float f_s[144], mud_s[144];
    __shared__ int   I_s[144];
    __shared__ float T_s[250];
    __shared__ float stat_s[8];       // 0 mean, 1 istd, 2 sc, 3 tm_c, 5 total
    __shared__ float spfc_s[10];
    __shared__ float tmg_s[16];

    const int bc = blockIdx.x, b = bc & 15, c = bc >> 4, t = threadIdx.x;

    // ================= prologue: all global loads =================
    const int   dm    = (t < 144) ? dmask[b * 2304 + t * 16 + c] : 0;
    const float wsc_v = wsconv[c];

    {   // own image: 196 float4 -> LDS (one load for t<196)
        const float4* x4 = (const float4*)(x + b * 784);
        if (t < 196) {
            const int r = t / 7, c4 = (t - r * 7) * 4;
            const float4 v = x4[t];
            float* dst = &xa_s[r * XSTR + c4];
            ((float2*)dst)[0] = make_float2(v.x, v.y);
            ((float2*)dst)[1] = make_float2(v.z, v.w);
        }
    }
    {   // W1 slice: contiguous 1440 floats
        const float4* wfc4 = (const float4*)wfc;
        for (int j4 = t; j4 < 360; j4 += 256)
            ((float4*)W1_s)[j4] = wfc4[c * 360 + j4];
    }
    {   // W2: rows q*16+c, float2
        const float2* wfc2 = (const float2*)wfc;
        for (int j2 = t; j2 < 720; j2 += 256) {
            const int q = j2 / 5, uh = j2 - q * 5;
            ((float2*)W2_s)[j2] = wfc2[(q * 16 + c) * 5 + uh];
        }
    }
    if (t < 25) w_s[t] = wconv[t * 16 + c];
    if (t < 10) spfc_s[t] = log1pf(expf(wsfc[t]));
    __syncthreads();

    // ====== fused conv+pool (own batch): t<144, one 2x2 cell each ======
    float best = 0.f, pn = 0.f;
    float psum_part = 0.f, psq_part = 0.f;
    if (t < 144) {
        const int h = t / 12, w2 = t - h * 12;
        const int y0 = 2 * h, x0 = 2 * w2;
        float xr[6][6];
#pragma unroll
        for (int i = 0; i < 6; i++) {
            const float2* row = (const float2*)&xa_s[(y0 + i) * XSTR + x0];
#pragma unroll
            for (int k = 0; k < 3; k++) {
                const float2 v = row[k];
                xr[i][2 * k] = v.x; xr[i][2 * k + 1] = v.y;
            }
        }
        float v00 = 0.f, v01 = 0.f, v10 = 0.f, v11 = 0.f;
#pragma unroll
        for (int i = 0; i < 5; i++)
#pragma unroll
            for (int j = 0; j < 5; j++) {
                const float wv = w_s[i * 5 + j];
                v00 = fmaf(xr[i][j],         wv, v00);
                v01 = fmaf(xr[i][j + 1],     wv, v01);
                v10 = fmaf(xr[i + 1][j],     wv, v10);
                v11 = fmaf(xr[i + 1][j + 1], wv, v11);
            }
        psum_part = v00 + v01 + v10 + v11;
        psq_part  = v00 * v00 + v01 * v01 + v10 * v10 + v11 * v11;
        best = v00; int arg = 0;
        if (v01 > best) { best = v01; arg = 1; }
        if (v10 > best) { best = v10; arg = 2; }
        if (v11 > best) { best = v11; arg = 3; }
        float pn0 = 0.f, pn1 = 0.f, pn2 = 0.f, pn3 = 0.f;
#pragma unroll
        for (int i = 0; i < 5; i++)
#pragma unroll
            for (int j = 0; j < 5; j++) {
                pn0 = fmaf(xr[i][j],         xr[i][j],         pn0);
                pn1 = fmaf(xr[i][j + 1],     xr[i][j + 1],     pn1);
                pn2 = fmaf(xr[i + 1][j],     xr[i + 1][j],     pn2);
                pn3 = fmaf(xr[i + 1][j + 1], xr[i + 1][j + 1], pn3);
            }
        pn = (arg == 0) ? pn0 : (arg == 1) ? pn1 : (arg == 2) ? pn2 : pn3;
        I_s[t] = (y0 + (arg >> 1)) * XSTR + (x0 + (arg & 1));
    }
    {
        const float wsum1 = wave_sum(psum_part), wsum2 = wave_sum(psq_part);
        if ((t & 63) == 0) { red_s[t >> 6] = wsum1; red_s[4 + (t >> 6)] = wsum2; }
    }
    __syncthreads();

    // ---- publish per-(b,c) BN partials ----
    if (t == 0) {
        const float ts = red_s[0] + red_s[1] + red_s[2] + red_s[3];
        const float tq = red_s[4] + red_s[5] + red_s[6] + red_s[7];
        const int ln = bc * 32;
        AG_ST(&dataA[ln], ts); AG_ST(&dataA[ln + 1], tq);
        asm volatile("s_waitcnt vmcnt(0)" ::: "memory");
        AG_ST(&flagA[ln], FLAG_MAGIC);
    }

    // ---- stats reducers: b==0 blocks, wave-0 lanes 0..15 (one per batch line) ----
    if (b == 0 && t < 16) {
        const int ln = (c * 16 + t) * 32;
        while (AG_LD(&flagA[ln]) != FLAG_MAGIC) __builtin_amdgcn_s_sleep(1);
        AG_ST(&flagA[ln], 0);
        float pa = AG_LD(&dataA[ln]), pb = AG_LD(&dataA[ln + 1]);
#pragma unroll
        for (int off = 8; off > 0; off >>= 1) {
            pa += __shfl_down(pa, off, 64);
            pb += __shfl_down(pb, off, 64);
        }
        pa = __shfl(pa, 0, 64); pb = __shfl(pb, 0, 64);   // broadcast sums
        const float mean = pa * (1.f / 9216.f);
        const float var  = pb * (1.f / 9216.f) - mean * mean;
        const float istd = 1.f / sqrtf(var + EPSV);
        const float scv  = log1pf(expf(wsc_v)) / (var + EPSV);
        AG_ST(&dataS[ln], mean); AG_ST(&dataS[ln + 1], istd); AG_ST(&dataS[ln + 2], scv);
        asm volatile("s_waitcnt vmcnt(0)" ::: "memory");
        AG_ST(&flagS[ln], FLAG_MAGIC);
    }

    // ---- overlap: gather XgT[p][q] (needs only I_s) while stats round-trip ----
    for (int e = t; e < 3600; e += 256) {
        const int p = e / 144, q = e - p * 144;
        XgT_s[p * QPAD + q] = xa_s[I_s[q] + (p / 5) * XSTR + (p % 5)];
    }

    // ---- consume stats ----
    if (t == 0) {
        const int ln = bc * 32;
        while (AG_LD(&flagS[ln]) != FLAG_MAGIC) __builtin_amdgcn_s_sleep(1);
        AG_ST(&flagS[ln], 0);
        stat_s[0] = AG_LD(&dataS[ln]);
        stat_s[1] = AG_LD(&dataS[ln + 1]);
        stat_s[2] = AG_LD(&dataS[ln + 2]);
    }
    __syncthreads();

    // ---- BN + ELU + dropout on pooled values (regs preserved) ----
    float trv = 0.f, mmv = 0.f;
    if (t < 144) {
        const float vn = (best - stat_s[0]) * stat_s[1];
        const float m  = (dm != 0) ? 1.f : 0.f;
        const float g  = vn > 0.f ? 1.f : expf(vn);
        const float el = vn > 0.f ? vn  : expm1f(vn);
        const float fq = DSCALE * m * g;
        const float md = DSCALE * m * el;
        f_s[t] = fq; mud_s[t] = md;
        trv = stat_s[2] * fq * fq * pn;   // sc * f^2 * ||patch||^2
        mmv = md * md;
    }
    {
        const float wt = wave_sum(trv), wm = wave_sum(mmv);
        if ((t & 63) == 0) { red_s[t >> 6] = wt; red_s[4 + (t >> 6)] = wm; }
    }
    __syncthreads();

    // ---- build fWT[u][q] = f[q] * W1[c,q,u]; fold tm_c ----
    for (int j = t; j < 1440; j += 256) {
        const int q = j / 10, u = j - q * 10;
        fWT_s[u * QPAD + q] = f_s[q] * W1_s[j];
    }
    if (t == 0)
        stat_s[3] = red_s[0] + red_s[1] + red_s[2] + red_s[3]
                  + red_s[4] + red_s[5] + red_s[6] + red_s[7];
    __syncthreads();

    // ---- T[p,u] = sum_q fWT[u,q] * XgT[p,q]  (b128 LDS reads) ----
    if (t < 250) {
        const int p = t / 10, u = t - (t / 10) * 10;
        const float4* fa = (const float4*)&fWT_s[u * QPAD];
        const float4* xg = (const float4*)&XgT_s[p * QPAD];
        float acc = 0.f;
#pragma unroll 6
        for (int k = 0; k < 36; k++) {
            const float4 a = fa[k], g4 = xg[k];
            acc = fmaf(a.x, g4.x, acc);
            acc = fmaf(a.y, g4.y, acc);
            acc = fmaf(a.z, g4.z, acc);
            acc = fmaf(a.w, g4.w, acc);
        }
        T_s[t] = acc;
    }
    __syncthreads();

    // ---- per-(b,c) output partials ----
    float sig_val = 0.f, mu_val = 0.f;
    if (t < 100) {
        const int u = t / 10, v = t - (t / 10) * 10;
        float acc = 0.f;
#pragma unroll
        for (int p = 0; p < 25; p++)
            acc = fmaf(T_s[p * 10 + u], T_s[p * 10 + v], acc);
        sig_val = stat_s[2] * acc;                 // sc * (T^T T)
    } else if (t < 110) {
        const int u = t - 100;
        float acc = 0.f;
#pragma unroll 8
        for (int q = 0; q < 144; q++)
            acc = fmaf(mud_s[q], W2_s[q * 10 + u], acc);
        mu_val = acc;
    }

    if (c != 0) {
        // ---- producer: publish partials, drain, flag ----
        if (t < 100)       AG_ST(&s1P[bc * 100 + t], sig_val);
        else if (t < 110)  AG_ST(&moP[bc * 10 + (t - 100)], mu_val);
        else if (t == 110) AG_ST(&tmP[bc], stat_s[3]);
        asm volatile("s_waitcnt vmcnt(0)" ::: "memory");
        __syncthreads();
        if (t == 0) AG_ST(&flagB[bc * 32], FLAG_MAGIC);
    } else {
        // ---- output reducer: spin on 15 peers, reduce, write out ----
        if (t < 15) {
            const int idx = ((t + 1) * 16 + b) * 32;
            while (AG_LD(&flagB[idx]) != FLAG_MAGIC) __builtin_amdgcn_s_sleep(2);
            AG_ST(&flagB[idx], 0);
        }
        __syncthreads();
        if (t < 15) tmg_s[t] = AG_LD(&tmP[(t + 1) * 16 + b]);
        __syncthreads();
        if (t == 0) {
            float a = stat_s[3];
            for (int i = 0; i < 15; i++) a += tmg_s[i];
            stat_s[5] = a;                          // total trace + mu.mu
        }
        __syncthreads();
        if (t < 100) {
            const int u = t / 10, v = t - (t / 10) * 10;
            float acc = sig_val;
#pragma unroll
            for (int cc = 1; cc < 16; cc++)
                acc += AG_LD(&s1P[(cc * 16 + b) * 100 + t]);
            if (u == v) acc += spfc_s[u] * stat_s[5];
            out[160 + b * 100 + t] = acc;
        } else if (t < 110) {
            const int u = t - 100;
            float acc = mu_val;
#pragma unroll
            for (int cc = 1; cc < 16; cc++)
                acc += AG_LD(&moP[(cc * 16 + b) * 10 + u]);
            out[b * 10 + u] = acc;
        }
    }
}

extern "C" void kernel_launch(void* const* d_in, const int* in_sizes, int n_in,
                              void* d_out, int out_size, void* d_ws, size_t ws_size,
                              hipStream_t stream) {
    const float* x      = (const float*)d_in[0];
    const int*   dmask  = (const int*)d_in[1];
    const float* wconv  = (const float*)d_in[2];
    const float* wsconv = (const float*)d_in[3];
    const float* wfc    = (const float*)d_in[4];
    const float* wsfc   = (const float*)d_in[5];
    float* out = (float*)d_out;

    float* ws    = (float*)d_ws;
    float* moP   = ws;                   // 2560
    float* s1P   = ws + 2560;            // 25600
    float* tmP   = ws + 28160;           // 256
    int*   flagB = (int*)(ws + 28416);   // 8192
    int*   flagA = (int*)(ws + 36608);   // 8192
    float* dataA = ws + 44800;           // 8192
    int*   flagS = (int*)(ws + 52992);   // 8192
    float* dataS = ws + 61184;           // 8192

    kFused<<<256, 256, 0, stream>>>(x, dmask, wconv, wsconv, wfc, wsfc,
                                    moP, s1P, tmP, flagB, flagA, dataA,
                                    flagS, dataS, out);
}

// Round 8
// 18.034 us; speedup vs baseline: 2.1458x; 1.0167x over previous
//
#include <hip/hip_runtime.h>
#include <math.h>

#define EPSV   1e-4f
#define DSCALE 1.25f   // 1/(1-0.2)

#define XSTR 30        // padded row stride (even -> float2-aligned windows)
#define XIMG 840       // 28*30 floats per image
#define QPAD 148       // padded q-stride for fWT/XgT (mult of 4 -> b128 aligned)
#define FLAG_MAGIC 0x1F2E3D4C

// ws layout (floats):
//   moP   [256][10]     @ 0       per-(c,b) mu_out partials   (bc = c*16+b)
//   s1P   [256][100]    @ 2560    per-(c,b) sc*T^T T partials
//   tmP   [256]         @ 28160   per-(c,b) tr_c + mm_c
//   flagB [256*32] int  @ 28416   output handshake (c!=0 -> c==0 reducer)
//   flagA [256*32] int  @ 36608   BN-partials: line (c*16+r), offset w
//   dataA [256*32]      @ 44800   (psum, psq) per (c,w) block line
//
// One-window stats: every block (c,bw) publishes (psum,psq) to dataA[c*16+bw],
// then lane r<16 sets flagA[line (c*16+r)][offset bw]. Every block (c,b)
// polls ITS line (16 consecutive ints -> one 64B load), resets it
// (single-consumer => replay-safe), loads the 16 dataA lines, and reduces
// with a 16-lane shfl_xor butterfly. No middleman block. DAG: A -> B -> out.

__device__ __forceinline__ float wave_sum(float v) {
#pragma unroll
    for (int off = 32; off > 0; off >>= 1) v += __shfl_down(v, off, 64);
    return v;
}

#define AG_LD(p)    __hip_atomic_load((p), __ATOMIC_RELAXED, __HIP_MEMORY_SCOPE_AGENT)
#define AG_ST(p, v) __hip_atomic_store((p), (v), __ATOMIC_RELAXED, __HIP_MEMORY_SCOPE_AGENT)

__global__ __launch_bounds__(256) void kFused(
    const float* __restrict__ x,      // [16,28,28,1]
    const int*   __restrict__ dmask,  // [16,12,12,16]
    const float* __restrict__ wconv,  // [5,5,1,16]
    const float* __restrict__ wsconv, // [16]
    const float* __restrict__ wfc,    // [2304,10]
    const float* __restrict__ wsfc,   // [10]
    float* __restrict__ moP, float* __restrict__ s1P, float* __restrict__ tmP,
    int* __restrict__ flagB, int* __restrict__ flagA, float* __restrict__ dataA,
    float* __restrict__ out)          // [160 mu | 1600 Sigma]
{
    __shared__ __align__(16) float xa_s[XIMG];        // own image only
    __shared__ __align__(16) float W1_s[1440];        // wfc rows c*144.. (W1 view)
    __shared__ __align__(8)  float W2_s[1440];        // spatial-major fc rows
    __shared__ __align__(16) float fWT_s[10 * QPAD];  // f[q]*W1[c,q,u], u-major
    __shared__ __align__(16) float XgT_s[25 * QPAD];  // gathered patches, p-major
    __shared__ float w_s[25];
    __shared__ float red_s[8];
    __shared__ float f_s[144], mud_s[144];
    __shared__ int   I_s[144];
    __shared__ float T_s[250];
    __shared__ float stat_s[8];       // 0 mean, 1 istd, 2 sc, 3 tm_c, 5 total
    __shared__ float spfc_s[10];
    __shared__ float tmg_s[16];

    const int bc = blockIdx.x, b = bc & 15, c = bc >> 4, t = threadIdx.x;

    // ================= prologue: all global loads =================
    const int   dm    = (t < 144) ? dmask[b * 2304 + t * 16 + c] : 0;
    const float wsc_v = wsconv[c];

    {   // own image: 196 float4 -> LDS
        const float4* x4 = (const float4*)(x + b * 784);
        if (t < 196) {
            const int r = t / 7, c4 = (t - r * 7) * 4;
            const float4 v = x4[t];
            float* dst = &xa_s[r * XSTR + c4];
            ((float2*)dst)[0] = make_float2(v.x, v.y);
            ((float2*)dst)[1] = make_float2(v.z, v.w);
        }
    }
    {   // W1 slice: contiguous 1440 floats
        const float4* wfc4 = (const float4*)wfc;
        for (int j4 = t; j4 < 360; j4 += 256)
            ((float4*)W1_s)[j4] = wfc4[c * 360 + j4];
    }
    {   // W2: rows q*16+c, float2
        const float2* wfc2 = (const float2*)wfc;
        for (int j2 = t; j2 < 720; j2 += 256) {
            const int q = j2 / 5, uh = j2 - q * 5;
            ((float2*)W2_s)[j2] = wfc2[(q * 16 + c) * 5 + uh];
        }
    }
    if (t < 25) w_s[t] = wconv[t * 16 + c];
    if (t < 10) spfc_s[t] = log1pf(expf(wsfc[t]));
    __syncthreads();

    // ====== fused conv+pool (own batch): t<144, one 2x2 cell each ======
    float best = 0.f, pn = 0.f;
    float psum_part = 0.f, psq_part = 0.f;
    if (t < 144) {
        const int h = t / 12, w2 = t - h * 12;
        const int y0 = 2 * h, x0 = 2 * w2;
        float xr[6][6];
#pragma unroll
        for (int i = 0; i < 6; i++) {
            const float2* row = (const float2*)&xa_s[(y0 + i) * XSTR + x0];
#pragma unroll
            for (int k = 0; k < 3; k++) {
                const float2 v = row[k];
                xr[i][2 * k] = v.x; xr[i][2 * k + 1] = v.y;
            }
        }
        float v00 = 0.f, v01 = 0.f, v10 = 0.f, v11 = 0.f;
#pragma unroll
        for (int i = 0; i < 5; i++)
#pragma unroll
            for (int j = 0; j < 5; j++) {
                const float wv = w_s[i * 5 + j];
                v00 = fmaf(xr[i][j],         wv, v00);
                v01 = fmaf(xr[i][j + 1],     wv, v01);
                v10 = fmaf(xr[i + 1][j],     wv, v10);
                v11 = fmaf(xr[i + 1][j + 1], wv, v11);
            }
        psum_part = v00 + v01 + v10 + v11;
        psq_part  = v00 * v00 + v01 * v01 + v10 * v10 + v11 * v11;
        best = v00; int arg = 0;
        if (v01 > best) { best = v01; arg = 1; }
        if (v10 > best) { best = v10; arg = 2; }
        if (v11 > best) { best = v11; arg = 3; }
        float pn0 = 0.f, pn1 = 0.f, pn2 = 0.f, pn3 = 0.f;
#pragma unroll
        for (int i = 0; i < 5; i++)
#pragma unroll
            for (int j = 0; j < 5; j++) {
                pn0 = fmaf(xr[i][j],         xr[i][j],         pn0);
                pn1 = fmaf(xr[i][j + 1],     xr[i][j + 1],     pn1);
                pn2 = fmaf(xr[i + 1][j],     xr[i + 1][j],     pn2);
                pn3 = fmaf(xr[i + 1][j + 1], xr[i + 1][j + 1], pn3);
            }
        pn = (arg == 0) ? pn0 : (arg == 1) ? pn1 : (arg == 2) ? pn2 : pn3;
        I_s[t] = (y0 + (arg >> 1)) * XSTR + (x0 + (arg & 1));
    }
    {
        const float wsum1 = wave_sum(psum_part), wsum2 = wave_sum(psq_part);
        if ((t & 63) == 0) { red_s[t >> 6] = wsum1; red_s[4 + (t >> 6)] = wsum2; }
    }
    __syncthreads();

    // ---- publish per-(b,c) BN partials + flag all 16 readers (wave 0) ----
    if (t == 0) {
        const float ts = red_s[0] + red_s[1] + red_s[2] + red_s[3];
        const float tq = red_s[4] + red_s[5] + red_s[6] + red_s[7];
        const int ln = bc * 32;
        AG_ST(&dataA[ln], ts); AG_ST(&dataA[ln + 1], tq);
    }
    asm volatile("s_waitcnt vmcnt(0)" ::: "memory");   // data before flags (wave 0)
    if (t < 16)
        AG_ST(&flagA[(c * 16 + t) * 32 + b], FLAG_MAGIC);

    // ---- overlap: gather XgT[p][q] (needs only I_s) while partials fly ----
    for (int e = t; e < 3600; e += 256) {
        const int p = e / 144, q = e - p * 144;
        XgT_s[p * QPAD + q] = xa_s[I_s[q] + (p / 5) * XSTR + (p % 5)];
    }

    // ---- consume stats: 16 lanes poll own line, butterfly-reduce ----
    if (t < 16) {
        int* fl = &flagA[(c * 16 + b) * 32 + t];
        while (AG_LD(fl) != FLAG_MAGIC) __builtin_amdgcn_s_sleep(1);
        AG_ST(fl, 0);
    }
    asm volatile("s_waitcnt vmcnt(0)" ::: "memory");   // flags seen before data read
    if (t < 16) {
        float pa = AG_LD(&dataA[(c * 16 + t) * 32]);
        float pb = AG_LD(&dataA[(c * 16 + t) * 32 + 1]);
#pragma unroll
        for (int off = 8; off > 0; off >>= 1) {
            pa += __shfl_xor(pa, off, 64);
            pb += __shfl_xor(pb, off, 64);
        }
        if (t == 0) {
            const float mean = pa * (1.f / 9216.f);
            const float var  = pb * (1.f / 9216.f) - mean * mean;
            stat_s[0] = mean;
            stat_s[1] = 1.f / sqrtf(var + EPSV);
            stat_s[2] = log1pf(expf(wsc_v)) / (var + EPSV);  // sc
        }
    }
    __syncthreads();

    // ---- BN + ELU + dropout on pooled values (regs preserved) ----
    float trv = 0.f, mmv = 0.f;
    if (t < 144) {
        const float vn = (best - stat_s[0]) * stat_s[1];
        const float m  = (dm != 0) ? 1.f : 0.f;
        const float g  = vn > 0.f ? 1.f : expf(vn);
        const float el = vn > 0.f ? vn  : expm1f(vn);
        const float fq = DSCALE * m * g;
        const float md = DSCALE * m * el;
        f_s[t] = fq; mud_s[t] = md;
        trv = stat_s[2] * fq * fq * pn;   // sc * f^2 * ||patch||^2
        mmv = md * md;
    }
    {
        const float wt = wave_sum(trv), wm = wave_sum(mmv);
        if ((t & 63) == 0) { red_s[t >> 6] = wt; red_s[4 + (t >> 6)] = wm; }
    }
    __syncthreads();

    // ---- build fWT[u][q] = f[q] * W1[c,q,u]; fold tm_c ----
    for (int j = t; j < 1440; j += 256) {
        const int q = j / 10, u = j - q * 10;
        fWT_s[u * QPAD + q] = f_s[q] * W1_s[j];
    }
    if (t == 0)
        stat_s[3] = red_s[0] + red_s[1] + red_s[2] + red_s[3]
                  + red_s[4] + red_s[5] + red_s[6] + red_s[7];
    __syncthreads();

    // ---- T[p,u] = sum_q fWT[u,q] * XgT[p,q]  (b128 LDS reads) ----
    if (t < 250) {
        const int p = t / 10, u = t - (t / 10) * 10;
        const float4* fa = (const float4*)&fWT_s[u * QPAD];
        const float4* xg = (const float4*)&XgT_s[p * QPAD];
        float acc = 0.f;
#pragma unroll 6
        for (int k = 0; k < 36; k++) {
            const float4 a = fa[k], g4 = xg[k];
            acc = fmaf(a.x, g4.x, acc);
            acc = fmaf(a.y, g4.y, acc);
            acc = fmaf(a.z, g4.z, acc);
            acc = fmaf(a.w, g4.w, acc);
        }
        T_s[t] = acc;
    }
    __syncthreads();

    // ---- per-(b,c) output partials ----
    float sig_val = 0.f, mu_val = 0.f;
    if (t < 100) {
        const int u = t / 10, v = t - (t / 10) * 10;
        float acc = 0.f;
#pragma unroll
        for (int p = 0; p < 25; p++)
            acc = fmaf(T_s[p * 10 + u], T_s[p * 10 + v], acc);
        sig_val = stat_s[2] * acc;                 // sc * (T^T T)
    } else if (t < 110) {
        const int u = t - 100;
        float acc = 0.f;
#pragma unroll 8
        for (int q = 0; q < 144; q++)
            acc = fmaf(mud_s[q], W2_s[q * 10 + u], acc);
        mu_val = acc;
    }

    if (c != 0) {
        // ---- producer: publish partials, drain, flag ----
        if (t < 100)       AG_ST(&s1P[bc * 100 + t], sig_val);
        else if (t < 110)  AG_ST(&moP[bc * 10 + (t - 100)], mu_val);
        else if (t == 110) AG_ST(&tmP[bc], stat_s[3]);
        asm volatile("s_waitcnt vmcnt(0)" ::: "memory");
        __syncthreads();
        if (t == 0) AG_ST(&flagB[bc * 32], FLAG_MAGIC);
    } else {
        // ---- output reducer: spin on 15 peers, reduce, write out ----
        if (t < 15) {
            const int idx = ((t + 1) * 16 + b) * 32;
            while (AG_LD(&flagB[idx]) != FLAG_MAGIC) __builtin_amdgcn_s_sleep(2);
            AG_ST(&flagB[idx], 0);
        }
        asm volatile("s_waitcnt vmcnt(0)" ::: "memory");
        __syncthreads();
        if (t < 15) tmg_s[t] = AG_LD(&tmP[(t + 1) * 16 + b]);
        __syncthreads();
        if (t == 0) {
            float a = stat_s[3];
            for (int i = 0; i < 15; i++) a += tmg_s[i];
            stat_s[5] = a;                          // total trace + mu.mu
        }
        __syncthreads();
        if (t < 100) {
            const int u = t / 10, v = t - (t / 10) * 10;
            float acc = sig_val;
#pragma unroll
            for (int cc = 1; cc < 16; cc++)
                acc += AG_LD(&s1P[(cc * 16 + b) * 100 + t]);
            if (u == v) acc += spfc_s[u] * stat_s[5];
            out[160 + b * 100 + t] = acc;
        } else if (t < 110) {
            const int u = t - 100;
            float acc = mu_val;
#pragma unroll
            for (int cc = 1; cc < 16; cc++)
                acc += AG_LD(&moP[(cc * 16 + b) * 10 + u]);
            out[b * 10 + u] = acc;
        }
    }
}

extern "C" void kernel_launch(void* const* d_in, const int* in_sizes, int n_in,
                              void* d_out, int out_size, void* d_ws, size_t ws_size,
                              hipStream_t stream) {
    const float* x      = (const float*)d_in[0];
    const int*   dmask  = (const int*)d_in[1];
    const float* wconv  = (const float*)d_in[2];
    const float* wsconv = (const float*)d_in[3];
    const float* wfc    = (const float*)d_in[4];
    const float* wsfc   = (const float*)d_in[5];
    float* out = (float*)d_out;

    float* ws    = (float*)d_ws;
    float* moP   = ws;                   // 2560
    float* s1P   = ws + 2560;            // 25600
    float* tmP   = ws + 28160;           // 256
    int*   flagB = (int*)(ws + 28416);   // 8192
    int*   flagA = (int*)(ws + 36608);   // 8192
    float* dataA = ws + 44800;           // 8192

    kFused<<<256, 256, 0, stream>>>(x, dmask, wconv, wsconv, wfc, wsfc,
                                    moP, s1P, tmP, flagB, flagA, dataA, out);
}